// Round 6
// baseline (47.513 us; speedup 1.0000x reference)
//
#include <hip/hip_runtime.h>
#include <hip/hip_fp16.h>

#define G_ 8
#define C_ 64
#define K_ 9
#define H_ 100
#define W_ 160
#define PG_ (H_ * W_ * G_)        // 128,000 (pixel,group) records per k
#define NX_ (H_ * W_ * G_ * C_)   // 5,120,000 x elements

// d_ws layout: [xh: NX_ * 2 B][rec: 9 * PG_ * 16 B]
#define XH_BYTES ((size_t)NX_ * 2)                  // 10,240,000 (16-B aligned)
#define REC_BYTES ((size_t)9 * PG_ * 16)            // 18,432,000
#define WS_NEED (XH_BYTES + REC_BYTES)

// ---------- Pass 1a: x f32 -> f16 (RNE) ----------
__global__ __launch_bounds__(256) void convert_kernel(
    const float* __restrict__ x, __half* __restrict__ xh)
{
    const int i = (int)(blockIdx.x * blockDim.x + threadIdx.x) * 8;
    if (i >= NX_) return;
    const float4 a = *(const float4*)(x + i);
    const float4 b = *(const float4*)(x + i + 4);
    __half2 h0 = __floats2half2_rn(a.x, a.y);
    __half2 h1 = __floats2half2_rn(a.z, a.w);
    __half2 h2 = __floats2half2_rn(b.x, b.y);
    __half2 h3 = __floats2half2_rn(b.z, b.w);
    uint4 o;
    o.x = *(unsigned*)&h0;
    o.y = *(unsigned*)&h1;
    o.z = *(unsigned*)&h2;
    o.w = *(unsigned*)&h3;
    *(uint4*)(xh + i) = o;
}

// ---------- Pass 1b: per-(pixel,group) scalar precompute, one lane each ----------
// rec[k][pixg] = { half2(w00,w01), half2(w10,w11), o00|o01<<16, o10|o11<<16 }
// where oXY = clamped (row*W + col) pixel index for corner XY; weights carry
// softmax(mask) modulation and border validity (0 weight when invalid).
__global__ __launch_bounds__(256) void prep_kernel(
    const float* __restrict__ offset, // [PG_ * 18]
    const float* __restrict__ mask,   // [PG_ * 9]
    uint4* __restrict__ rec)          // [9][PG_]
{
    const int pixg = (int)(blockIdx.x * blockDim.x + threadIdx.x);
    if (pixg >= PG_) return;
    const int pix = pixg >> 3;
    const int w = pix % W_;
    const int h = pix / W_;

    const float* mptr = mask   + (size_t)pixg * K_;
    const float* optr = offset + (size_t)pixg * (K_ * 2);

    float mv[K_];
    float mmax = -1e30f;
#pragma unroll
    for (int k = 0; k < K_; ++k) { mv[k] = mptr[k]; mmax = fmaxf(mmax, mv[k]); }
    float msum = 0.f;
#pragma unroll
    for (int k = 0; k < K_; ++k) { mv[k] = __expf(mv[k] - mmax); msum += mv[k]; }
    const float minv = 1.f / msum;

#pragma unroll
    for (int k = 0; k < K_; ++k) {
        const float lh = (float)(h + k / 3 - 1) + optr[2 * k];
        const float lw = (float)(w + k % 3 - 1) + optr[2 * k + 1];
        const float fh0 = floorf(lh), fw0 = floorf(lw);
        const float th = lh - fh0, tw = lw - fw0;
        const int h0 = (int)fh0, w0 = (int)fw0;
        const float m = mv[k] * minv;

        const float wh0 = (h0 >= 0  && h0 < H_    ) ? (1.f - th) * m : 0.f;
        const float wh1 = (h0 >= -1 && h0 < H_ - 1) ? th * m         : 0.f;
        const float cw0 = (w0 >= 0  && w0 < W_    ) ? (1.f - tw)     : 0.f;
        const float cw1 = (w0 >= -1 && w0 < W_ - 1) ? tw             : 0.f;
        const float w00 = wh0 * cw0, w01 = wh0 * cw1;
        const float w10 = wh1 * cw0, w11 = wh1 * cw1;

        const int hc0 = min(max(h0,     0), H_ - 1);
        const int hc1 = min(max(h0 + 1, 0), H_ - 1);
        const int wc0 = min(max(w0,     0), W_ - 1);
        const int wc1 = min(max(w0 + 1, 0), W_ - 1);
        const unsigned o00 = (unsigned)(hc0 * W_ + wc0);
        const unsigned o01 = (unsigned)(hc0 * W_ + wc1);
        const unsigned o10 = (unsigned)(hc1 * W_ + wc0);
        const unsigned o11 = (unsigned)(hc1 * W_ + wc1);

        __half2 p0 = __floats2half2_rn(w00, w01);  // .x=w00(lo), .y=w01(hi)
        __half2 p1 = __floats2half2_rn(w10, w11);
        uint4 r;
        r.x = *(unsigned*)&p0;
        r.y = *(unsigned*)&p1;
        r.z = o00 | (o01 << 16);
        r.w = o10 | (o11 << 16);
        rec[(size_t)k * PG_ + pixg] = r;
    }
}

// ---------- Pass 2: pure gather + hfma2. One wave per pixel; octet per group;
// lane owns 8 channels. 1024-thread blocks; XCD banding (1000 = 8*125). ----------
__global__ __launch_bounds__(1024) void dcn_gather_kernel(
    const __half* __restrict__ xh,   // [H*W][G*C] f16
    const uint4* __restrict__ rec,   // [9][PG_]
    float* __restrict__ out)         // [H*W][G*C]
{
    const int bid = (int)blockIdx.x;
    const int vb  = (bid & 7) * 125 + (bid >> 3);
    const int pix = vb * 16 + (int)(threadIdx.x >> 6);
    if (pix >= H_ * W_) return;
    const int lane = threadIdx.x & 63;
    const int g  = lane >> 3;
    const int li = lane & 7;
    const int pixg = pix * G_ + g;

    // lane's channel base, in bytes (pixel record = G*C*2 = 1024 B)
    const char* xb = (const char*)xh + (g * C_ + li * 8) * 2;
    const uint4* recp = rec + pixg;

    __half2 acc[3][4];
#pragma unroll
    for (int gr = 0; gr < 3; ++gr)
#pragma unroll
        for (int p = 0; p < 4; ++p)
            acc[gr][p] = __half2(__half(0.f), __half(0.f));

#pragma unroll
    for (int k = 0; k < K_; ++k) {
        const int gr = k / 3;  // compile-time under unroll
        const uint4 r = recp[(size_t)k * PG_];

        const unsigned d00 = __builtin_amdgcn_perm(r.x, r.x, 0x01000100u); // dup w00
        const unsigned d01 = __builtin_amdgcn_perm(r.x, r.x, 0x03020302u); // dup w01
        const unsigned d10 = __builtin_amdgcn_perm(r.y, r.y, 0x01000100u); // dup w10
        const unsigned d11 = __builtin_amdgcn_perm(r.y, r.y, 0x03020302u); // dup w11
        const __half2 W00 = *(const __half2*)&d00;
        const __half2 W01 = *(const __half2*)&d01;
        const __half2 W10 = *(const __half2*)&d10;
        const __half2 W11 = *(const __half2*)&d11;

        const unsigned o00 = (r.z & 0xffffu) << 10;  // byte offsets (<<10 = *1024)
        const unsigned o01 = (r.z >> 16) << 10;
        const unsigned o10 = (r.w & 0xffffu) << 10;
        const unsigned o11 = (r.w >> 16) << 10;

        const uint4 q00 = *(const uint4*)(xb + o00);
        const uint4 q01 = *(const uint4*)(xb + o01);
        const uint4 q10 = *(const uint4*)(xb + o10);
        const uint4 q11 = *(const uint4*)(xb + o11);

#pragma unroll
        for (int p = 0; p < 4; ++p) {
            const __half2 v00 = ((const __half2*)&q00)[p];
            const __half2 v01 = ((const __half2*)&q01)[p];
            const __half2 v10 = ((const __half2*)&q10)[p];
            const __half2 v11 = ((const __half2*)&q11)[p];
            __half2 a = acc[gr][p];
            a = __hfma2(v00, W00, a);
            a = __hfma2(v01, W01, a);
            a = __hfma2(v10, W10, a);
            a = __hfma2(v11, W11, a);
            acc[gr][p] = a;
        }
    }

    float2 s0, s1, s2, s3;
    {
        float2 t;
        s0 = __half22float2(acc[0][0]);
        t = __half22float2(acc[1][0]); s0.x += t.x; s0.y += t.y;
        t = __half22float2(acc[2][0]); s0.x += t.x; s0.y += t.y;
        s1 = __half22float2(acc[0][1]);
        t = __half22float2(acc[1][1]); s1.x += t.x; s1.y += t.y;
        t = __half22float2(acc[2][1]); s1.x += t.x; s1.y += t.y;
        s2 = __half22float2(acc[0][2]);
        t = __half22float2(acc[1][2]); s2.x += t.x; s2.y += t.y;
        t = __half22float2(acc[2][2]); s2.x += t.x; s2.y += t.y;
        s3 = __half22float2(acc[0][3]);
        t = __half22float2(acc[1][3]); s3.x += t.x; s3.y += t.y;
        t = __half22float2(acc[2][3]); s3.x += t.x; s3.y += t.y;
    }

    float* op = out + (size_t)pixg * C_ + li * 8;
    *(float4*)op       = make_float4(s0.x, s0.y, s1.x, s1.y);
    *(float4*)(op + 4) = make_float4(s2.x, s2.y, s3.x, s3.y);
}

// ---------- Fallback: f32 gather, used if ws too small ----------
__global__ __launch_bounds__(256) void dcn_f32_kernel(
    const float* __restrict__ x,
    const float* __restrict__ offset,
    const float* __restrict__ mask,
    float* __restrict__ out)
{
    const int pix = (int)((blockIdx.x * blockDim.x + threadIdx.x) >> 6);
    if (pix >= H_ * W_) return;
    const int lane = threadIdx.x & 63;
    const int g  = lane >> 3;
    const int li = lane & 7;
    const int w = pix % W_;
    const int h = pix / W_;

    const int pixg = pix * G_ + g;
    const float* mptr = mask   + (size_t)pixg * K_;
    const float* optr = offset + (size_t)pixg * (K_ * 2);

    float mv[K_];
    float mmax = -1e30f;
#pragma unroll
    for (int k = 0; k < K_; ++k) { mv[k] = mptr[k]; mmax = fmaxf(mmax, mv[k]); }
    float msum = 0.f;
#pragma unroll
    for (int k = 0; k < K_; ++k) { mv[k] = __expf(mv[k] - mmax); msum += mv[k]; }
    const float minv = 1.f / msum;

    const float* xg = x + (size_t)g * C_ + li * 4;

    float a0 = 0.f, a1 = 0.f, a2 = 0.f, a3 = 0.f;
    float a4 = 0.f, a5 = 0.f, a6 = 0.f, a7 = 0.f;

#pragma unroll
    for (int k = 0; k < K_; ++k) {
        const float lh = (float)(h + k / 3 - 1) + optr[2 * k];
        const float lw = (float)(w + k % 3 - 1) + optr[2 * k + 1];
        const float fh0 = floorf(lh), fw0 = floorf(lw);
        const float th = lh - fh0, tw = lw - fw0;
        const int h0 = (int)fh0, w0 = (int)fw0;
        const float m = mv[k] * minv;

        const float wh0 = (h0 >= 0  && h0 < H_    ) ? (1.f - th) * m : 0.f;
        const float wh1 = (h0 >= -1 && h0 < H_ - 1) ? th * m         : 0.f;
        const float cw0 = (w0 >= 0  && w0 < W_    ) ? (1.f - tw)     : 0.f;
        const float cw1 = (w0 >= -1 && w0 < W_ - 1) ? tw             : 0.f;
        const float w00 = wh0 * cw0, w01 = wh0 * cw1;
        const float w10 = wh1 * cw0, w11 = wh1 * cw1;

        const int hc0 = min(max(h0,     0), H_ - 1);
        const int hc1 = min(max(h0 + 1, 0), H_ - 1);
        const int wc0 = min(max(w0,     0), W_ - 1);
        const int wc1 = min(max(w0 + 1, 0), W_ - 1);
        const int r0 = hc0 * W_, r1 = hc1 * W_;

        const float* p00 = xg + (size_t)(r0 + wc0) * (G_ * C_);
        const float* p01 = xg + (size_t)(r0 + wc1) * (G_ * C_);
        const float* p10 = xg + (size_t)(r1 + wc0) * (G_ * C_);
        const float* p11 = xg + (size_t)(r1 + wc1) * (G_ * C_);

#define ACC8(P, WT)                                                        \
        {                                                                  \
            const float4 lo = *(const float4*)(P);                         \
            const float4 hi = *(const float4*)((P) + 32);                  \
            a0 += lo.x * (WT); a1 += lo.y * (WT);                          \
            a2 += lo.z * (WT); a3 += lo.w * (WT);                          \
            a4 += hi.x * (WT); a5 += hi.y * (WT);                          \
            a6 += hi.z * (WT); a7 += hi.w * (WT);                          \
        }
        ACC8(p00, w00)
        ACC8(p01, w01)
        ACC8(p10, w10)
        ACC8(p11, w11)
#undef ACC8
    }

    float* op = out + (size_t)pixg * C_ + li * 4;
    *(float4*)op        = make_float4(a0, a1, a2, a3);
    *(float4*)(op + 32) = make_float4(a4, a5, a6, a7);
}

extern "C" void kernel_launch(void* const* d_in, const int* in_sizes, int n_in,
                              void* d_out, int out_size, void* d_ws, size_t ws_size,
                              hipStream_t stream) {
    const float* x      = (const float*)d_in[0];
    const float* offset = (const float*)d_in[1];
    const float* mask   = (const float*)d_in[2];
    float* out          = (float*)d_out;

    if (ws_size >= WS_NEED) {
        __half* xh = (__half*)d_ws;
        uint4* rec = (uint4*)((char*)d_ws + XH_BYTES);

        convert_kernel<<<NX_ / 8 / 256, 256, 0, stream>>>(x, xh);
        prep_kernel<<<PG_ / 256, 256, 0, stream>>>(offset, mask, rec);
        dcn_gather_kernel<<<(H_ * W_) / 16, 1024, 0, stream>>>(xh, rec, out);
    } else {
        const int total_threads = H_ * W_ * 64;
        dcn_f32_kernel<<<(total_threads + 255) / 256, 256, 0, stream>>>(
            x, offset, mask, out);
    }
}